// Round 2
// baseline (393.235 us; speedup 1.0000x reference)
//
#include <hip/hip_runtime.h>
#include <stdint.h>

#define HD   256
#define SEQ  4096
#define NB   4
#define NROW (NB * SEQ)   // 16384

typedef __attribute__((ext_vector_type(8))) short short8;
typedef __attribute__((ext_vector_type(4))) float f32x4;

__device__ __forceinline__ unsigned short f2bf(float f) {
  union { float f; unsigned u; } v; v.f = f;
  unsigned u = v.u;
  u += 0x7fffu + ((u >> 16) & 1u);
  return (unsigned short)(u >> 16);
}
__device__ __forceinline__ float bf2f(unsigned short h) {
  union { float f; unsigned u; } v; v.u = ((unsigned)h) << 16;
  return v.f;
}

__device__ __forceinline__ f32x4 mfma16(short8 a, short8 b, f32x4 c) {
  return __builtin_amdgcn_mfma_f32_16x16x32_bf16(a, b, c, 0, 0, 0);
}

__device__ __forceinline__ void gload_lds16(const void* g, void* l) {
  __builtin_amdgcn_global_load_lds((const __attribute__((address_space(1))) void*)g,
                                   (__attribute__((address_space(3))) void*)l,
                                   16, 0, 0);
}

// ---------------------------------------------------------------------------
// Kernel 1: transpose + hi/lo split the weight matrices.
// WTh/WTl layout: [mat][o][k], o = out col, k = in dim.  W input is [k][o].
// ---------------------------------------------------------------------------
__global__ __launch_bounds__(256) void prep_w_kernel(
    const float* __restrict__ Wq, const float* __restrict__ Wk,
    const float* __restrict__ Wv,
    unsigned short* __restrict__ WTh, unsigned short* __restrict__ WTl)
{
  int flat = blockIdx.x * 256 + threadIdx.x;   // 0 .. 3*65536-1
  int mat = flat >> 16;
  int e   = flat & 65535;
  int o   = e >> 8;
  int k   = e & 255;
  const float* W = (mat == 0) ? Wq : (mat == 1) ? Wk : Wv;
  float v = W[k * 256 + o];
  unsigned short h = f2bf(v);
  WTh[flat] = h;
  WTl[flat] = f2bf(v - bf2f(h));
}

// ---------------------------------------------------------------------------
// Kernel 2: QKV projection. C = x @ W + b via split bf16 MFMA (3-product).
// Block: 64 rows x 256 outs, 4 waves (wave w owns cols [64w,64w+64)).
// mat 0 -> Qh/Ql, 1 -> Kh/Kl, 2 -> VT[b][h][s] (transposed, hi only).
// ---------------------------------------------------------------------------
__global__ __launch_bounds__(256) void proj_kernel(
    const float* __restrict__ x,
    const unsigned short* __restrict__ WTh, const unsigned short* __restrict__ WTl,
    const float* __restrict__ bq, const float* __restrict__ bk,
    const float* __restrict__ bv,
    unsigned short* __restrict__ Qh, unsigned short* __restrict__ Ql,
    unsigned short* __restrict__ Kh, unsigned short* __restrict__ Kl,
    unsigned short* __restrict__ VT)
{
  const int mat = blockIdx.y;
  const int r0  = blockIdx.x << 6;     // 64-row tile
  const int tid = threadIdx.x;
  const int w    = tid >> 6;
  const int lane = tid & 63;
  const int lr   = lane & 15;
  const int hi4  = lane >> 4;
  const int r4   = hi4 << 2;

  const unsigned short* wth = WTh + (mat << 16);
  const unsigned short* wtl = WTl + (mat << 16);

  f32x4 acc[4][4] = {};

#pragma unroll
  for (int ks = 0; ks < 8; ++ks) {
    short8 ah[4], al[4];
#pragma unroll
    for (int m = 0; m < 4; ++m) {
      const float* xp = x + (r0 + (m << 4) + lr) * 256 + (ks << 5) + (hi4 << 3);
      f32x4 a0 = *(const f32x4*)xp;
      f32x4 a1 = *(const f32x4*)(xp + 4);
      short8 hh, ll;
#pragma unroll
      for (int j = 0; j < 4; ++j) {
        unsigned short h0 = f2bf(a0[j]);
        hh[j]     = (short)h0;
        ll[j]     = (short)f2bf(a0[j] - bf2f(h0));
        unsigned short h1 = f2bf(a1[j]);
        hh[4 + j] = (short)h1;
        ll[4 + j] = (short)f2bf(a1[j] - bf2f(h1));
      }
      ah[m] = hh; al[m] = ll;
    }
#pragma unroll
    for (int n = 0; n < 4; ++n) {
      int o = (w << 6) + (n << 4) + lr;
      const unsigned short* bp = wth + o * 256 + (ks << 5) + (hi4 << 3);
      const unsigned short* lp = wtl + o * 256 + (ks << 5) + (hi4 << 3);
      short8 bh = *(const short8*)bp;
      short8 bl = *(const short8*)lp;
#pragma unroll
      for (int m = 0; m < 4; ++m) acc[m][n] = mfma16(ah[m], bh, acc[m][n]);
#pragma unroll
      for (int m = 0; m < 4; ++m) acc[m][n] = mfma16(al[m], bh, acc[m][n]);
#pragma unroll
      for (int m = 0; m < 4; ++m) acc[m][n] = mfma16(ah[m], bl, acc[m][n]);
    }
  }

  const float* bias = (mat == 0) ? bq : (mat == 1) ? bk : bv;
#pragma unroll
  for (int n = 0; n < 4; ++n) {
    int col = (w << 6) + (n << 4) + lr;
    float bb = bias[col];
#pragma unroll
    for (int m = 0; m < 4; ++m) {
#pragma unroll
      for (int reg = 0; reg < 4; ++reg) {
        int row = r0 + (m << 4) + r4 + reg;     // global row in [0,16384)
        float val = acc[m][n][reg] + bb;
        unsigned short h = f2bf(val);
        if (mat == 0) {
          Qh[row * 256 + col] = h;
          Ql[row * 256 + col] = f2bf(val - bf2f(h));
        } else if (mat == 1) {
          Kh[row * 256 + col] = h;
          Kl[row * 256 + col] = f2bf(val - bf2f(h));
        } else {
          int b = row >> 12, s = row & 4095;
          VT[(b << 20) + (col << 12) + s] = h;
        }
      }
    }
  }
}

// ---------------------------------------------------------------------------
// Kernel 3: causal flash attention.
// Block = (batch, q-tile of 64 rows), 4 waves x 16 q-rows, BK=64.
// Kh/Kl [64][256] and VT [256][64] staged in LDS via global_load_lds with
// pre-swizzled source (XOR chunk^row&7) -> conflict-free ds_read_b128.
// XCD swizzle: logical tile = ((bx&7)<<5)|(bx>>3) so each XCD's 32 blocks
// share one batch's K/V panels (low-qt XCDs fit their panel in 4MB L2).
// ---------------------------------------------------------------------------
__global__ __launch_bounds__(256) void attn_kernel(
    const unsigned short* __restrict__ Qh, const unsigned short* __restrict__ Ql,
    const unsigned short* __restrict__ Kh, const unsigned short* __restrict__ Kl,
    const unsigned short* __restrict__ VT, float* __restrict__ out)
{
  __shared__ __align__(16) unsigned short sKh[64 * 256];
  __shared__ __align__(16) unsigned short sKl[64 * 256];
  __shared__ __align__(16) unsigned short sVT[256 * 64];
  __shared__ __align__(16) unsigned short sP[4 * 16 * 64];

  const int bx    = blockIdx.x;
  const int logical = ((bx & 7) << 5) | (bx >> 3);   // XCD-aware remap
  const int batch = logical >> 6;
  const int qt    = logical & 63;
  const int tid   = threadIdx.x;
  const int w     = tid >> 6;
  const int lane  = tid & 63;
  const int lr    = lane & 15;
  const int hi4   = lane >> 4;
  const int r4    = hi4 << 2;
  const int q0    = qt << 6;

  const unsigned short* Kh_b = Kh + (batch << 20);
  const unsigned short* Kl_b = Kl + (batch << 20);
  const unsigned short* VT_b = VT + (batch << 20);

  // Q fragments for this wave's 16 rows (hi+lo), K=256 -> 8 k-steps.
  const int qrow_g = (batch << 12) + q0 + (w << 4) + lr;
  short8 qh[8], ql[8];
#pragma unroll
  for (int ks = 0; ks < 8; ++ks) {
    qh[ks] = *(const short8*)(Qh + qrow_g * 256 + (ks << 5) + (hi4 << 3));
    ql[ks] = *(const short8*)(Ql + qrow_g * 256 + (ks << 5) + (hi4 << 3));
  }

  float m_[4], l_[4];
#pragma unroll
  for (int r = 0; r < 4; ++r) { m_[r] = -1e30f; l_[r] = 0.0f; }
  f32x4 oacc[16] = {};

  unsigned short* pw = sP + (w << 10);

  for (int kt = 0; kt <= qt; ++kt) {
    // ---- stage K (hi/lo) and VT tiles, swizzled source / linear LDS dest
#pragma unroll
    for (int it = 0; it < 8; ++it) {
      int id = it * 256 + tid;
      int r  = id >> 5, cb = id & 31;
      int srcc = (cb ^ (r & 7)) << 3;
      const unsigned short* gk = Kh_b + (((kt << 6) + r) << 8) + srcc;
      gload_lds16(gk, sKh + id * 8);
      const unsigned short* gl = Kl_b + (((kt << 6) + r) << 8) + srcc;
      gload_lds16(gl, sKl + id * 8);
      int r2 = id >> 3, cb2 = id & 7;
      const unsigned short* gv = VT_b + (r2 << 12) + (kt << 6) + ((cb2 ^ (r2 & 7)) << 3);
      gload_lds16(gv, sVT + id * 8);
    }
    __syncthreads();

    // ---- scores: S = Qh*Kh + Ql*Kh + Qh*Kl
    f32x4 sacc[4] = {};
#pragma unroll
    for (int ks = 0; ks < 8; ++ks) {
      short8 khf[4], klf[4];
#pragma unroll
      for (int n = 0; n < 4; ++n) {
        int krow = (n << 4) + lr;
        int swz  = (((ks << 2) + hi4) ^ (krow & 7)) << 3;
        khf[n] = *(const short8*)(sKh + krow * 256 + swz);
        klf[n] = *(const short8*)(sKl + krow * 256 + swz);
      }
      __builtin_amdgcn_s_setprio(1);
#pragma unroll
      for (int n = 0; n < 4; ++n) sacc[n] = mfma16(qh[ks], khf[n], sacc[n]);
#pragma unroll
      for (int n = 0; n < 4; ++n) sacc[n] = mfma16(ql[ks], khf[n], sacc[n]);
#pragma unroll
      for (int n = 0; n < 4; ++n) sacc[n] = mfma16(qh[ks], klf[n], sacc[n]);
      __builtin_amdgcn_s_setprio(0);
    }

    // ---- causal mask (only the diagonal tile needs it; BQ == BK aligned)
    if (kt == qt) {
#pragma unroll
      for (int n = 0; n < 4; ++n) {
        int kg = (kt << 6) + (n << 4) + lr;
#pragma unroll
        for (int reg = 0; reg < 4; ++reg) {
          int qg = q0 + (w << 4) + r4 + reg;
          if (kg > qg) sacc[n][reg] = -1e30f;
        }
      }
    }

    // ---- online softmax (rows live on 16-lane groups; 4 rows per lane)
    float mx[4];
#pragma unroll
    for (int reg = 0; reg < 4; ++reg)
      mx[reg] = fmaxf(fmaxf(sacc[0][reg], sacc[1][reg]),
                      fmaxf(sacc[2][reg], sacc[3][reg]));
#pragma unroll
    for (int d = 1; d < 16; d <<= 1) {
#pragma unroll
      for (int reg = 0; reg < 4; ++reg)
        mx[reg] = fmaxf(mx[reg], __shfl_xor(mx[reg], d, 64));
    }
    float sc[4];
#pragma unroll
    for (int reg = 0; reg < 4; ++reg) {
      float mn = fmaxf(m_[reg], mx[reg]);
      sc[reg] = __expf(m_[reg] - mn);
      m_[reg] = mn;
    }
    float rs[4] = {0.f, 0.f, 0.f, 0.f};
    unsigned short pb[4][4];
#pragma unroll
    for (int n = 0; n < 4; ++n) {
#pragma unroll
      for (int reg = 0; reg < 4; ++reg) {
        float p = __expf(sacc[n][reg] - m_[reg]);
        rs[reg] += p;
        pb[n][reg] = f2bf(p);
      }
    }
#pragma unroll
    for (int d = 1; d < 16; d <<= 1) {
#pragma unroll
      for (int reg = 0; reg < 4; ++reg)
        rs[reg] += __shfl_xor(rs[reg], d, 64);
    }
#pragma unroll
    for (int reg = 0; reg < 4; ++reg)
      l_[reg] = l_[reg] * sc[reg] + rs[reg];
#pragma unroll
    for (int hf = 0; hf < 16; ++hf) {
#pragma unroll
      for (int reg = 0; reg < 4; ++reg) oacc[hf][reg] *= sc[reg];
    }

    // ---- P -> per-wave LDS (swizzled), read back as A fragments
#pragma unroll
    for (int n = 0; n < 4; ++n) {
#pragma unroll
      for (int reg = 0; reg < 4; ++reg) {
        int prow = r4 + reg;
        int pcol = (n << 4) + lr;
        pw[prow * 64 + (pcol ^ ((prow & 7) << 3))] = pb[n][reg];
      }
    }
    short8 pa[2];
#pragma unroll
    for (int ks2 = 0; ks2 < 2; ++ks2) {
      int c0 = (ks2 << 5) + (hi4 << 3);
      pa[ks2] = *(const short8*)(pw + lr * 64 + (c0 ^ ((lr & 7) << 3)));
    }

    // ---- PV: O += P @ V   (V fragments from swizzled VT tile)
    __builtin_amdgcn_s_setprio(1);
#pragma unroll
    for (int hf = 0; hf < 16; ++hf) {
#pragma unroll
      for (int ks2 = 0; ks2 < 2; ++ks2) {
        int vrow = (hf << 4) + lr;
        int swz  = (((ks2 << 2) + hi4) ^ (vrow & 7)) << 3;
        short8 vb = *(const short8*)(sVT + vrow * 64 + swz);
        oacc[hf] = mfma16(pa[ks2], vb, oacc[hf]);
      }
    }
    __builtin_amdgcn_s_setprio(0);
    __syncthreads();
  }

  // ---- epilogue: O / l
  float inv_l[4];
#pragma unroll
  for (int reg = 0; reg < 4; ++reg) inv_l[reg] = 1.0f / l_[reg];
#pragma unroll
  for (int hf = 0; hf < 16; ++hf) {
    int col = (hf << 4) + lr;
#pragma unroll
    for (int reg = 0; reg < 4; ++reg) {
      int qg = q0 + (w << 4) + r4 + reg;
      out[((batch << 12) + qg) * 256 + col] = oacc[hf][reg] * inv_l[reg];
    }
  }
}

// ---------------------------------------------------------------------------
extern "C" void kernel_launch(void* const* d_in, const int* in_sizes, int n_in,
                              void* d_out, int out_size, void* d_ws, size_t ws_size,
                              hipStream_t stream) {
  (void)in_sizes; (void)n_in; (void)out_size; (void)ws_size;
  const float* x  = (const float*)d_in[0];
  const float* Wq = (const float*)d_in[1];
  const float* bq = (const float*)d_in[2];
  const float* Wk = (const float*)d_in[3];
  const float* bk = (const float*)d_in[4];
  const float* Wv = (const float*)d_in[5];
  const float* bv = (const float*)d_in[6];
  float* out = (float*)d_out;

  unsigned short* WTh = (unsigned short*)d_ws;          // [3][256][256]
  unsigned short* WTl = WTh + 3 * 65536;
  unsigned short* Qh  = WTl + 3 * 65536;                // [16384][256]
  unsigned short* Ql  = Qh + NROW * HD;
  unsigned short* Kh  = Ql + NROW * HD;
  unsigned short* Kl  = Kh + NROW * HD;
  unsigned short* VT  = Kl + NROW * HD;                 // [4][256][4096]

  hipLaunchKernelGGL(prep_w_kernel, dim3(768), dim3(256), 0, stream,
                     Wq, Wk, Wv, WTh, WTl);
  hipLaunchKernelGGL(proj_kernel, dim3(256, 3), dim3(256), 0, stream,
                     x, WTh, WTl, bq, bk, bv, Qh, Ql, Kh, Kl, VT);
  hipLaunchKernelGGL(attn_kernel, dim3(256), dim3(256), 0, stream,
                     Qh, Ql, Kh, Kl, VT, out);
}

// Round 3
// 317.196 us; speedup vs baseline: 1.2397x; 1.2397x over previous
//
#include <hip/hip_runtime.h>
#include <stdint.h>

#define HD   256
#define SEQ  4096
#define NB   4
#define NROW (NB * SEQ)   // 16384

typedef __attribute__((ext_vector_type(8))) short short8;
typedef __attribute__((ext_vector_type(4))) float f32x4;
typedef _Float16 v8h __attribute__((ext_vector_type(8)));

__device__ __forceinline__ unsigned short f2bf(float f) {
  union { float f; unsigned u; } v; v.f = f;
  unsigned u = v.u;
  u += 0x7fffu + ((u >> 16) & 1u);
  return (unsigned short)(u >> 16);
}
__device__ __forceinline__ float bf2f(unsigned short h) {
  union { float f; unsigned u; } v; v.u = ((unsigned)h) << 16;
  return v.f;
}
__device__ __forceinline__ unsigned short f2h(float f) {
  union { _Float16 h; unsigned short u; } v;
  v.h = (_Float16)f;
  return v.u;
}

__device__ __forceinline__ f32x4 mfma16(short8 a, short8 b, f32x4 c) {
  return __builtin_amdgcn_mfma_f32_16x16x32_bf16(a, b, c, 0, 0, 0);
}
__device__ __forceinline__ f32x4 mfma16h(v8h a, v8h b, f32x4 c) {
  return __builtin_amdgcn_mfma_f32_16x16x32_f16(a, b, c, 0, 0, 0);
}

__device__ __forceinline__ void gload_lds16(const void* g, void* l) {
  __builtin_amdgcn_global_load_lds((const __attribute__((address_space(1))) void*)g,
                                   (__attribute__((address_space(3))) void*)l,
                                   16, 0, 0);
}

// ---------------------------------------------------------------------------
// Kernel 0: split x (f32) into bf16 hi/lo once (proj reads these directly).
// ---------------------------------------------------------------------------
__global__ __launch_bounds__(256) void prep_x_kernel(
    const float* __restrict__ x,
    unsigned short* __restrict__ xh, unsigned short* __restrict__ xl)
{
  int i = blockIdx.x * 256 + threadIdx.x;      // 8 elems per thread
  const float* p = x + i * 8;
  f32x4 a0 = *(const f32x4*)p;
  f32x4 a1 = *(const f32x4*)(p + 4);
  short8 hh, ll;
#pragma unroll
  for (int j = 0; j < 4; ++j) {
    unsigned short h0 = f2bf(a0[j]);
    hh[j]     = (short)h0;
    ll[j]     = (short)f2bf(a0[j] - bf2f(h0));
    unsigned short h1 = f2bf(a1[j]);
    hh[4 + j] = (short)h1;
    ll[4 + j] = (short)f2bf(a1[j] - bf2f(h1));
  }
  *(short8*)(xh + i * 8) = hh;
  *(short8*)(xl + i * 8) = ll;
}

// ---------------------------------------------------------------------------
// Kernel 1: transpose + hi/lo split the weight matrices (bf16).
// ---------------------------------------------------------------------------
__global__ __launch_bounds__(256) void prep_w_kernel(
    const float* __restrict__ Wq, const float* __restrict__ Wk,
    const float* __restrict__ Wv,
    unsigned short* __restrict__ WTh, unsigned short* __restrict__ WTl)
{
  int flat = blockIdx.x * 256 + threadIdx.x;   // 0 .. 3*65536-1
  int mat = flat >> 16;
  int e   = flat & 65535;
  int o   = e >> 8;
  int k   = e & 255;
  const float* W = (mat == 0) ? Wq : (mat == 1) ? Wk : Wv;
  float v = W[k * 256 + o];
  unsigned short h = f2bf(v);
  WTh[flat] = h;
  WTl[flat] = f2bf(v - bf2f(h));
}

// ---------------------------------------------------------------------------
// Kernel 2: QKV projection via split-bf16 3-product MFMA; outputs fp16.
// mat 0 -> Qf [row][h], 1 -> Kf [row][h], 2 -> VT [b][h][s] (transposed).
// ---------------------------------------------------------------------------
__global__ __launch_bounds__(256) void proj_kernel(
    const unsigned short* __restrict__ xh, const unsigned short* __restrict__ xl,
    const unsigned short* __restrict__ WTh, const unsigned short* __restrict__ WTl,
    const float* __restrict__ bq, const float* __restrict__ bk,
    const float* __restrict__ bv,
    unsigned short* __restrict__ Qf, unsigned short* __restrict__ Kf,
    unsigned short* __restrict__ VT)
{
  const int mat = blockIdx.y;
  const int r0  = blockIdx.x << 6;     // 64-row tile
  const int tid = threadIdx.x;
  const int w    = tid >> 6;
  const int lane = tid & 63;
  const int lr   = lane & 15;
  const int hi4  = lane >> 4;
  const int r4   = hi4 << 2;

  const unsigned short* wth = WTh + (mat << 16);
  const unsigned short* wtl = WTl + (mat << 16);

  f32x4 acc[4][4] = {};

#pragma unroll
  for (int ks = 0; ks < 8; ++ks) {
    short8 ah[4], al[4];
#pragma unroll
    for (int m = 0; m < 4; ++m) {
      int off = (r0 + (m << 4) + lr) * 256 + (ks << 5) + (hi4 << 3);
      ah[m] = *(const short8*)(xh + off);
      al[m] = *(const short8*)(xl + off);
    }
#pragma unroll
    for (int n = 0; n < 4; ++n) {
      int o = (w << 6) + (n << 4) + lr;
      short8 bh = *(const short8*)(wth + o * 256 + (ks << 5) + (hi4 << 3));
      short8 bl = *(const short8*)(wtl + o * 256 + (ks << 5) + (hi4 << 3));
#pragma unroll
      for (int m = 0; m < 4; ++m) acc[m][n] = mfma16(ah[m], bh, acc[m][n]);
#pragma unroll
      for (int m = 0; m < 4; ++m) acc[m][n] = mfma16(al[m], bh, acc[m][n]);
#pragma unroll
      for (int m = 0; m < 4; ++m) acc[m][n] = mfma16(ah[m], bl, acc[m][n]);
    }
  }

  const float* bias = (mat == 0) ? bq : (mat == 1) ? bk : bv;
#pragma unroll
  for (int n = 0; n < 4; ++n) {
    int col = (w << 6) + (n << 4) + lr;
    float bb = bias[col];
#pragma unroll
    for (int m = 0; m < 4; ++m) {
#pragma unroll
      for (int reg = 0; reg < 4; ++reg) {
        int row = r0 + (m << 4) + r4 + reg;     // global row in [0,16384)
        float val = acc[m][n][reg] + bb;
        unsigned short h = f2h(val);
        if (mat == 0) {
          Qf[row * 256 + col] = h;
        } else if (mat == 1) {
          Kf[row * 256 + col] = h;
        } else {
          int b = row >> 12, s = row & 4095;
          VT[(b << 20) + (col << 12) + s] = h;
        }
      }
    }
  }
}

// ---------------------------------------------------------------------------
// Kernel 3: causal flash attention, fp16 QK/PV, double-buffered staging.
// Block = (batch, q-tile of 64 rows), 4 waves x 16 q-rows, BK=64.
// K [64][256] and VT [256][64] staged via global_load_lds with pre-swizzled
// source (chunk ^ row&7) -> conflict-free ds_read_b128. 2 LDS buffers:
// issue stage(kt+1) -> compute(kt) -> __syncthreads (drains vmcnt) -> flip.
// ---------------------------------------------------------------------------
__global__ __launch_bounds__(256) void attn_kernel(
    const unsigned short* __restrict__ Qf, const unsigned short* __restrict__ Kf,
    const unsigned short* __restrict__ VT, float* __restrict__ out)
{
  __shared__ __align__(16) unsigned short sK[2][64 * 256];
  __shared__ __align__(16) unsigned short sV[2][256 * 64];
  __shared__ __align__(16) unsigned short sP[4 * 16 * 64];

  const int bx      = blockIdx.x;
  const int logical = ((bx & 7) << 5) | (bx >> 3);   // XCD-aware remap
  const int batch   = logical >> 6;
  const int qt      = logical & 63;
  const int tid     = threadIdx.x;
  const int w       = tid >> 6;
  const int lane    = tid & 63;
  const int lr      = lane & 15;
  const int hi4     = lane >> 4;
  const int r4      = hi4 << 2;
  const int q0      = qt << 6;

  const unsigned short* Kf_b = Kf + (batch << 20);
  const unsigned short* VT_b = VT + (batch << 20);

  auto stage = [&](int buf, int kt) {
#pragma unroll
    for (int it = 0; it < 8; ++it) {
      int id = it * 256 + tid;
      int r  = id >> 5, cb = id & 31;
      gload_lds16(Kf_b + (((kt << 6) + r) << 8) + ((cb ^ (r & 7)) << 3),
                  &sK[buf][id * 8]);
      int r2 = id >> 3, cb2 = id & 7;
      gload_lds16(VT_b + (r2 << 12) + (kt << 6) + ((cb2 ^ (r2 & 7)) << 3),
                  &sV[buf][id * 8]);
    }
  };

  // Q fragments for this wave's 16 rows, K=256 -> 8 k-steps.
  const int qrow_g = (batch << 12) + q0 + (w << 4) + lr;
  v8h qf[8];
#pragma unroll
  for (int ks = 0; ks < 8; ++ks)
    qf[ks] = *(const v8h*)(Qf + qrow_g * 256 + (ks << 5) + (hi4 << 3));

  float m_[4], l_[4];
#pragma unroll
  for (int r = 0; r < 4; ++r) { m_[r] = -1e30f; l_[r] = 0.0f; }
  f32x4 oacc[16] = {};

  unsigned short* pw = sP + (w << 10);

  stage(0, 0);
  __syncthreads();
  int cur = 0;

  for (int kt = 0; kt <= qt; ++kt) {
    // ---- prefetch next K/V tile into the other buffer
    if (kt < qt) stage(cur ^ 1, kt + 1);

    const unsigned short* sKc = sK[cur];
    const unsigned short* sVc = sV[cur];

    // ---- scores: S = Q @ K^T (fp16 single product)
    f32x4 sacc[4] = {};
#pragma unroll
    for (int ks = 0; ks < 8; ++ks) {
      v8h kf[4];
#pragma unroll
      for (int n = 0; n < 4; ++n) {
        int krow = (n << 4) + lr;
        int swz  = (((ks << 2) + hi4) ^ (krow & 7)) << 3;
        kf[n] = *(const v8h*)(sKc + krow * 256 + swz);
      }
      __builtin_amdgcn_s_setprio(1);
#pragma unroll
      for (int n = 0; n < 4; ++n) sacc[n] = mfma16h(qf[ks], kf[n], sacc[n]);
      __builtin_amdgcn_s_setprio(0);
    }

    // ---- causal mask (diagonal tile only; BQ == BK aligned)
    if (kt == qt) {
#pragma unroll
      for (int n = 0; n < 4; ++n) {
        int kg = (kt << 6) + (n << 4) + lr;
#pragma unroll
        for (int reg = 0; reg < 4; ++reg) {
          int qg = q0 + (w << 4) + r4 + reg;
          if (kg > qg) sacc[n][reg] = -1e30f;
        }
      }
    }

    // ---- online softmax (rows live on 16-lane groups; 4 rows per lane)
    float mx[4];
#pragma unroll
    for (int reg = 0; reg < 4; ++reg)
      mx[reg] = fmaxf(fmaxf(sacc[0][reg], sacc[1][reg]),
                      fmaxf(sacc[2][reg], sacc[3][reg]));
#pragma unroll
    for (int d = 1; d < 16; d <<= 1) {
#pragma unroll
      for (int reg = 0; reg < 4; ++reg)
        mx[reg] = fmaxf(mx[reg], __shfl_xor(mx[reg], d, 64));
    }
    float sc[4];
#pragma unroll
    for (int reg = 0; reg < 4; ++reg) {
      float mn = fmaxf(m_[reg], mx[reg]);
      sc[reg] = __expf(m_[reg] - mn);
      m_[reg] = mn;
    }
    float rs[4] = {0.f, 0.f, 0.f, 0.f};
    unsigned short pb[4][4];
#pragma unroll
    for (int n = 0; n < 4; ++n) {
#pragma unroll
      for (int reg = 0; reg < 4; ++reg) {
        float p = __expf(sacc[n][reg] - m_[reg]);
        rs[reg] += p;
        pb[n][reg] = f2h(p);
      }
    }
#pragma unroll
    for (int d = 1; d < 16; d <<= 1) {
#pragma unroll
      for (int reg = 0; reg < 4; ++reg)
        rs[reg] += __shfl_xor(rs[reg], d, 64);
    }
#pragma unroll
    for (int reg = 0; reg < 4; ++reg)
      l_[reg] = l_[reg] * sc[reg] + rs[reg];
#pragma unroll
    for (int hf = 0; hf < 16; ++hf) {
#pragma unroll
      for (int reg = 0; reg < 4; ++reg) oacc[hf][reg] *= sc[reg];
    }

    // ---- P -> per-wave LDS (swizzled), read back as A fragments
#pragma unroll
    for (int n = 0; n < 4; ++n) {
#pragma unroll
      for (int reg = 0; reg < 4; ++reg) {
        int prow = r4 + reg;
        int pcol = (n << 4) + lr;
        pw[prow * 64 + (pcol ^ ((prow & 7) << 3))] = pb[n][reg];
      }
    }
    v8h pa[2];
#pragma unroll
    for (int ks2 = 0; ks2 < 2; ++ks2) {
      int c0 = (ks2 << 5) + (hi4 << 3);
      pa[ks2] = *(const v8h*)(pw + lr * 64 + (c0 ^ ((lr & 7) << 3)));
    }

    // ---- PV: O += P @ V
    __builtin_amdgcn_s_setprio(1);
#pragma unroll
    for (int hf = 0; hf < 16; ++hf) {
#pragma unroll
      for (int ks2 = 0; ks2 < 2; ++ks2) {
        int vrow = (hf << 4) + lr;
        int swz  = (((ks2 << 2) + hi4) ^ (vrow & 7)) << 3;
        v8h vb = *(const v8h*)(sVc + vrow * 64 + swz);
        oacc[hf] = mfma16h(pa[ks2], vb, oacc[hf]);
      }
    }
    __builtin_amdgcn_s_setprio(0);

    __syncthreads();   // drains vmcnt(0): next buffer staged & this buffer free
    cur ^= 1;
  }

  // ---- epilogue: O / l
  float inv_l[4];
#pragma unroll
  for (int reg = 0; reg < 4; ++reg) inv_l[reg] = 1.0f / l_[reg];
#pragma unroll
  for (int hf = 0; hf < 16; ++hf) {
    int col = (hf << 4) + lr;
#pragma unroll
    for (int reg = 0; reg < 4; ++reg) {
      int qg = q0 + (w << 4) + r4 + reg;
      out[((batch << 12) + qg) * 256 + col] = oacc[hf][reg] * inv_l[reg];
    }
  }
}

// ---------------------------------------------------------------------------
extern "C" void kernel_launch(void* const* d_in, const int* in_sizes, int n_in,
                              void* d_out, int out_size, void* d_ws, size_t ws_size,
                              hipStream_t stream) {
  (void)in_sizes; (void)n_in; (void)out_size; (void)ws_size;
  const float* x  = (const float*)d_in[0];
  const float* Wq = (const float*)d_in[1];
  const float* bq = (const float*)d_in[2];
  const float* Wk = (const float*)d_in[3];
  const float* bk = (const float*)d_in[4];
  const float* Wv = (const float*)d_in[5];
  const float* bv = (const float*)d_in[6];
  float* out = (float*)d_out;

  unsigned short* WTh = (unsigned short*)d_ws;          // [3][256][256] bf16
  unsigned short* WTl = WTh + 3 * 65536;
  unsigned short* xh  = WTl + 3 * 65536;                // [16384][256] bf16
  unsigned short* xl  = xh + NROW * HD;
  unsigned short* Qf  = xl + NROW * HD;                 // [16384][256] fp16
  unsigned short* Kf  = Qf + NROW * HD;
  unsigned short* VT  = Kf + NROW * HD;                 // [4][256][4096] fp16

  hipLaunchKernelGGL(prep_x_kernel, dim3(2048), dim3(256), 0, stream,
                     x, xh, xl);
  hipLaunchKernelGGL(prep_w_kernel, dim3(768), dim3(256), 0, stream,
                     Wq, Wk, Wv, WTh, WTl);
  hipLaunchKernelGGL(proj_kernel, dim3(256, 3), dim3(256), 0, stream,
                     xh, xl, WTh, WTl, bq, bk, bv, Qf, Kf, VT);
  hipLaunchKernelGGL(attn_kernel, dim3(256), dim3(256), 0, stream,
                     Qf, Kf, VT, out);
}

// Round 5
// 232.356 us; speedup vs baseline: 1.6924x; 1.3651x over previous
//
#include <hip/hip_runtime.h>
#include <stdint.h>

#define HD   256
#define SEQ  4096
#define NB   4
#define NROW (NB * SEQ)   // 16384

typedef __attribute__((ext_vector_type(8))) short short8;
typedef __attribute__((ext_vector_type(4))) float f32x4;
typedef _Float16 v8h __attribute__((ext_vector_type(8)));

__device__ __forceinline__ unsigned short f2bf(float f) {
  union { float f; unsigned u; } v; v.f = f;
  unsigned u = v.u;
  u += 0x7fffu + ((u >> 16) & 1u);
  return (unsigned short)(u >> 16);
}
__device__ __forceinline__ float bf2f(unsigned short h) {
  union { float f; unsigned u; } v; v.u = ((unsigned)h) << 16;
  return v.f;
}
__device__ __forceinline__ unsigned short f2h(float f) {
  union { _Float16 h; unsigned short u; } v;
  v.h = (_Float16)f;
  return v.u;
}

__device__ __forceinline__ f32x4 mfma16(short8 a, short8 b, f32x4 c) {
  return __builtin_amdgcn_mfma_f32_16x16x32_bf16(a, b, c, 0, 0, 0);
}
__device__ __forceinline__ f32x4 mfma16h(v8h a, v8h b, f32x4 c) {
  return __builtin_amdgcn_mfma_f32_16x16x32_f16(a, b, c, 0, 0, 0);
}

__device__ __forceinline__ void gload_lds16(const void* g, void* l) {
  __builtin_amdgcn_global_load_lds((const __attribute__((address_space(1))) void*)g,
                                   (__attribute__((address_space(3))) void*)l,
                                   16, 0, 0);
}

// ---------------------------------------------------------------------------
// Kernel 0: split x (f32) into bf16 hi/lo once.
// ---------------------------------------------------------------------------
__global__ __launch_bounds__(256) void prep_x_kernel(
    const float* __restrict__ x,
    unsigned short* __restrict__ xh, unsigned short* __restrict__ xl)
{
  int i = blockIdx.x * 256 + threadIdx.x;      // 8 elems per thread
  const float* p = x + i * 8;
  f32x4 a0 = *(const f32x4*)p;
  f32x4 a1 = *(const f32x4*)(p + 4);
  short8 hh, ll;
#pragma unroll
  for (int j = 0; j < 4; ++j) {
    unsigned short h0 = f2bf(a0[j]);
    hh[j]     = (short)h0;
    ll[j]     = (short)f2bf(a0[j] - bf2f(h0));
    unsigned short h1 = f2bf(a1[j]);
    hh[4 + j] = (short)h1;
    ll[4 + j] = (short)f2bf(a1[j] - bf2f(h1));
  }
  *(short8*)(xh + i * 8) = hh;
  *(short8*)(xl + i * 8) = ll;
}

// ---------------------------------------------------------------------------
// Kernel 1: transpose + hi/lo split the weight matrices (bf16).
// ---------------------------------------------------------------------------
__global__ __launch_bounds__(256) void prep_w_kernel(
    const float* __restrict__ Wq, const float* __restrict__ Wk,
    const float* __restrict__ Wv,
    unsigned short* __restrict__ WTh, unsigned short* __restrict__ WTl)
{
  int flat = blockIdx.x * 256 + threadIdx.x;   // 0 .. 3*65536-1
  int mat = flat >> 16;
  int e   = flat & 65535;
  int o   = e >> 8;
  int k   = e & 255;
  const float* W = (mat == 0) ? Wq : (mat == 1) ? Wk : Wv;
  float v = W[k * 256 + o];
  unsigned short h = f2bf(v);
  WTh[flat] = h;
  WTl[flat] = f2bf(v - bf2f(h));
}

// ---------------------------------------------------------------------------
// Kernel 2: QKV projection via split-bf16 3-product MFMA; outputs fp16.
// mat 0 -> Qf [row][h], 1 -> Kf [row][h], 2 -> VT [b][h][s] (transposed).
// ---------------------------------------------------------------------------
__global__ __launch_bounds__(256) void proj_kernel(
    const unsigned short* __restrict__ xh, const unsigned short* __restrict__ xl,
    const unsigned short* __restrict__ WTh, const unsigned short* __restrict__ WTl,
    const float* __restrict__ bq, const float* __restrict__ bk,
    const float* __restrict__ bv,
    unsigned short* __restrict__ Qf, unsigned short* __restrict__ Kf,
    unsigned short* __restrict__ VT)
{
  const int mat = blockIdx.y;
  const int r0  = blockIdx.x << 6;     // 64-row tile
  const int tid = threadIdx.x;
  const int w    = tid >> 6;
  const int lane = tid & 63;
  const int lr   = lane & 15;
  const int hi4  = lane >> 4;
  const int r4   = hi4 << 2;

  const unsigned short* wth = WTh + (mat << 16);
  const unsigned short* wtl = WTl + (mat << 16);

  f32x4 acc[4][4] = {};

#pragma unroll
  for (int ks = 0; ks < 8; ++ks) {
    short8 ah[4], al[4];
#pragma unroll
    for (int m = 0; m < 4; ++m) {
      int off = (r0 + (m << 4) + lr) * 256 + (ks << 5) + (hi4 << 3);
      ah[m] = *(const short8*)(xh + off);
      al[m] = *(const short8*)(xl + off);
    }
#pragma unroll
    for (int n = 0; n < 4; ++n) {
      int o = (w << 6) + (n << 4) + lr;
      short8 bh = *(const short8*)(wth + o * 256 + (ks << 5) + (hi4 << 3));
      short8 bl = *(const short8*)(wtl + o * 256 + (ks << 5) + (hi4 << 3));
#pragma unroll
      for (int m = 0; m < 4; ++m) acc[m][n] = mfma16(ah[m], bh, acc[m][n]);
#pragma unroll
      for (int m = 0; m < 4; ++m) acc[m][n] = mfma16(al[m], bh, acc[m][n]);
#pragma unroll
      for (int m = 0; m < 4; ++m) acc[m][n] = mfma16(ah[m], bl, acc[m][n]);
    }
  }

  const float* bias = (mat == 0) ? bq : (mat == 1) ? bk : bv;
#pragma unroll
  for (int n = 0; n < 4; ++n) {
    int col = (w << 6) + (n << 4) + lr;
    float bb = bias[col];
#pragma unroll
    for (int m = 0; m < 4; ++m) {
#pragma unroll
      for (int reg = 0; reg < 4; ++reg) {
        int row = r0 + (m << 4) + r4 + reg;     // global row in [0,16384)
        float val = acc[m][n][reg] + bb;
        unsigned short h = f2h(val);
        if (mat == 0) {
          Qf[row * 256 + col] = h;
        } else if (mat == 1) {
          Kf[row * 256 + col] = h;
        } else {
          int b = row >> 12, s = row & 4095;
          VT[(b << 20) + (col << 12) + s] = h;
        }
      }
    }
  }
}

// ---------------------------------------------------------------------------
// Kernel 3: causal flash attention, split-K into 2 halves per q-tile.
// 512 blocks = (batch, qt, half). xcd = bx&7 -> batch = xcd>>1, half = xcd&1.
// rank = bx>>3: qt = r<32 ? 63-r : r-32  (co-resident CU pair sums to 65).
// Single-buffer staging (72 KB LDS) -> 2 blocks/CU = 2 waves/SIMD (TLP).
// Writes partial (m, l, O-unnormalized) to workspace; merge_kernel combines.
// ---------------------------------------------------------------------------
__global__ __launch_bounds__(256, 2) void attn_kernel(
    const unsigned short* __restrict__ Qf, const unsigned short* __restrict__ Kf,
    const unsigned short* __restrict__ VT,
    float* __restrict__ Opart, float* __restrict__ Mpart, float* __restrict__ Lpart)
{
  __shared__ __align__(16) unsigned short sK[64 * 256];
  __shared__ __align__(16) unsigned short sV[256 * 64];
  __shared__ __align__(16) unsigned short sP[4 * 16 * 64];

  const int bx    = blockIdx.x;
  const int xcd   = bx & 7;
  const int r     = bx >> 3;                  // 0..63
  const int batch = xcd >> 1;
  const int half  = xcd & 1;
  const int qt    = (r < 32) ? (63 - r) : (r - 32);
  const int mid   = (qt + 2) >> 1;
  const int k0    = half ? mid : 0;
  const int k1    = half ? (qt + 1) : mid;

  const int tid  = threadIdx.x;
  const int w    = tid >> 6;
  const int lane = tid & 63;
  const int lr   = lane & 15;
  const int hi4  = lane >> 4;
  const int r4   = hi4 << 2;
  const int q0   = qt << 6;

  const unsigned short* Kf_b = Kf + (batch << 20);
  const unsigned short* VT_b = VT + (batch << 20);

  // Q fragments for this wave's 16 rows, K=256 -> 8 k-steps.
  const int qrow_g = (batch << 12) + q0 + (w << 4) + lr;
  v8h qf[8];
#pragma unroll
  for (int ks = 0; ks < 8; ++ks)
    qf[ks] = *(const v8h*)(Qf + qrow_g * 256 + (ks << 5) + (hi4 << 3));

  float m_[4], l_[4];
#pragma unroll
  for (int i = 0; i < 4; ++i) { m_[i] = -1e30f; l_[i] = 0.0f; }
  f32x4 oacc[16] = {};

  unsigned short* pw = sP + (w << 10);

  for (int kt = k0; kt < k1; ++kt) {
    // ---- stage K [64][256] and VT [256][64], pre-swizzled source
#pragma unroll
    for (int it = 0; it < 8; ++it) {
      int id = it * 256 + tid;
      int rr = id >> 5, cb = id & 31;
      gload_lds16(Kf_b + (((kt << 6) + rr) << 8) + ((cb ^ (rr & 7)) << 3),
                  sK + id * 8);
      int r2 = id >> 3, cb2 = id & 7;
      gload_lds16(VT_b + (r2 << 12) + (kt << 6) + ((cb2 ^ (r2 & 7)) << 3),
                  sV + id * 8);
    }
    __syncthreads();

    // ---- scores: S = Q @ K^T (fp16)
    f32x4 sacc[4] = {};
#pragma unroll
    for (int ks = 0; ks < 8; ++ks) {
      v8h kf[4];
#pragma unroll
      for (int n = 0; n < 4; ++n) {
        int krow = (n << 4) + lr;
        int swz  = (((ks << 2) + hi4) ^ (krow & 7)) << 3;
        kf[n] = *(const v8h*)(sK + krow * 256 + swz);
      }
      __builtin_amdgcn_s_setprio(1);
#pragma unroll
      for (int n = 0; n < 4; ++n) sacc[n] = mfma16h(qf[ks], kf[n], sacc[n]);
      __builtin_amdgcn_s_setprio(0);
    }

    // ---- causal mask (diagonal tile only)
    if (kt == qt) {
#pragma unroll
      for (int n = 0; n < 4; ++n) {
        int kg = (kt << 6) + (n << 4) + lr;
#pragma unroll
        for (int reg = 0; reg < 4; ++reg) {
          int qg = q0 + (w << 4) + r4 + reg;
          if (kg > qg) sacc[n][reg] = -1e30f;
        }
      }
    }

    // ---- online softmax (rows on 16-lane groups; 4 rows per lane)
    float mx[4];
#pragma unroll
    for (int reg = 0; reg < 4; ++reg)
      mx[reg] = fmaxf(fmaxf(sacc[0][reg], sacc[1][reg]),
                      fmaxf(sacc[2][reg], sacc[3][reg]));
#pragma unroll
    for (int d = 1; d < 16; d <<= 1) {
#pragma unroll
      for (int reg = 0; reg < 4; ++reg)
        mx[reg] = fmaxf(mx[reg], __shfl_xor(mx[reg], d, 64));
    }
    float sc[4];
#pragma unroll
    for (int reg = 0; reg < 4; ++reg) {
      float mn = fmaxf(m_[reg], mx[reg]);
      sc[reg] = __expf(m_[reg] - mn);
      m_[reg] = mn;
    }
    float rs[4] = {0.f, 0.f, 0.f, 0.f};
    unsigned short pb[4][4];
#pragma unroll
    for (int n = 0; n < 4; ++n) {
#pragma unroll
      for (int reg = 0; reg < 4; ++reg) {
        float p = __expf(sacc[n][reg] - m_[reg]);
        rs[reg] += p;
        pb[n][reg] = f2h(p);
      }
    }
#pragma unroll
    for (int d = 1; d < 16; d <<= 1) {
#pragma unroll
      for (int reg = 0; reg < 4; ++reg)
        rs[reg] += __shfl_xor(rs[reg], d, 64);
    }
#pragma unroll
    for (int reg = 0; reg < 4; ++reg)
      l_[reg] = l_[reg] * sc[reg] + rs[reg];
#pragma unroll
    for (int hf = 0; hf < 16; ++hf) {
#pragma unroll
      for (int reg = 0; reg < 4; ++reg) oacc[hf][reg] *= sc[reg];
    }

    // ---- P -> per-wave LDS (swizzled), read back as A fragments
#pragma unroll
    for (int n = 0; n < 4; ++n) {
#pragma unroll
      for (int reg = 0; reg < 4; ++reg) {
        int prow = r4 + reg;
        int pcol = (n << 4) + lr;
        pw[prow * 64 + (pcol ^ ((prow & 7) << 3))] = pb[n][reg];
      }
    }
    v8h pa[2];
#pragma unroll
    for (int ks2 = 0; ks2 < 2; ++ks2) {
      int c0 = (ks2 << 5) + (hi4 << 3);
      pa[ks2] = *(const v8h*)(pw + lr * 64 + (c0 ^ ((lr & 7) << 3)));
    }

    // ---- PV: O += P @ V
    __builtin_amdgcn_s_setprio(1);
#pragma unroll
    for (int hf = 0; hf < 16; ++hf) {
#pragma unroll
      for (int ks2 = 0; ks2 < 2; ++ks2) {
        int vrow = (hf << 4) + lr;
        int swz  = (((ks2 << 2) + hi4) ^ (vrow & 7)) << 3;
        v8h vb = *(const v8h*)(sV + vrow * 64 + swz);
        oacc[hf] = mfma16h(pa[ks2], vb, oacc[hf]);
      }
    }
    __builtin_amdgcn_s_setprio(0);
    __syncthreads();
  }

  // ---- epilogue: write partial (O unnormalized, m, l)
  const int pidx = (((batch << 6) + qt) << 1) + half;
  float* Op = Opart + (size_t)pidx * (64 * 256);
#pragma unroll
  for (int hf = 0; hf < 16; ++hf) {
    int col = (hf << 4) + lr;
#pragma unroll
    for (int reg = 0; reg < 4; ++reg) {
      int row = (w << 4) + r4 + reg;
      Op[row * 256 + col] = oacc[hf][reg];
    }
  }
  if (lr == 0) {
#pragma unroll
    for (int reg = 0; reg < 4; ++reg) {
      int row = (w << 4) + r4 + reg;
      Mpart[pidx * 64 + row] = m_[reg];
      Lpart[pidx * 64 + row] = l_[reg];
    }
  }
}

// ---------------------------------------------------------------------------
// Kernel 4: merge the two split-K partials per q-row.
// ---------------------------------------------------------------------------
__global__ __launch_bounds__(256) void merge_kernel(
    const float* __restrict__ Opart, const float* __restrict__ Mpart,
    const float* __restrict__ Lpart, float* __restrict__ out)
{
  int t = blockIdx.x * 256 + threadIdx.x;     // row*32 + cslot
  int row = t >> 5, cslot = t & 31;
  int batch = row >> 12, wi = row & 4095;
  int qt = wi >> 6, rr = wi & 63;
  int idx = ((batch << 6) + qt) << 1;
  float m0 = Mpart[idx * 64 + rr],      l0 = Lpart[idx * 64 + rr];
  float m1 = Mpart[(idx + 1) * 64 + rr], l1 = Lpart[(idx + 1) * 64 + rr];
  float M  = fmaxf(m0, m1);
  float a0 = __expf(m0 - M), a1 = __expf(m1 - M);
  float inv = 1.0f / (a0 * l0 + a1 * l1);
  const float* O0 = Opart + (size_t)idx * (64 * 256) + rr * 256 + cslot * 8;
  const float* O1 = O0 + 64 * 256;
  float* op = out + (size_t)row * 256 + cslot * 8;
  f32x4 v00 = *(const f32x4*)O0,      v01 = *(const f32x4*)(O0 + 4);
  f32x4 v10 = *(const f32x4*)O1,      v11 = *(const f32x4*)(O1 + 4);
  f32x4 r0, r1;
#pragma unroll
  for (int j = 0; j < 4; ++j) {
    r0[j] = (a0 * v00[j] + a1 * v10[j]) * inv;
    r1[j] = (a0 * v01[j] + a1 * v11[j]) * inv;
  }
  *(f32x4*)op = r0;
  *(f32x4*)(op + 4) = r1;
}

// ---------------------------------------------------------------------------
extern "C" void kernel_launch(void* const* d_in, const int* in_sizes, int n_in,
                              void* d_out, int out_size, void* d_ws, size_t ws_size,
                              hipStream_t stream) {
  (void)in_sizes; (void)n_in; (void)out_size; (void)ws_size;
  const float* x  = (const float*)d_in[0];
  const float* Wq = (const float*)d_in[1];
  const float* bq = (const float*)d_in[2];
  const float* Wk = (const float*)d_in[3];
  const float* bk = (const float*)d_in[4];
  const float* Wv = (const float*)d_in[5];
  const float* bv = (const float*)d_in[6];
  float* out = (float*)d_out;

  unsigned short* WTh = (unsigned short*)d_ws;          // [3][256][256] bf16
  unsigned short* WTl = WTh + 3 * 65536;
  unsigned short* xh  = WTl + 3 * 65536;                // [16384][256] bf16
  unsigned short* xl  = xh + NROW * HD;
  unsigned short* Qf  = xl + NROW * HD;                 // [16384][256] fp16
  unsigned short* Kf  = Qf + NROW * HD;
  unsigned short* VT  = Kf + NROW * HD;                 // [4][256][4096] fp16
  float* Opart = (float*)(VT + (size_t)NB * HD * SEQ);  // [512][64][256] f32
  float* Mpart = Opart + (size_t)512 * 64 * 256;        // [512][64]
  float* Lpart = Mpart + 512 * 64;

  hipLaunchKernelGGL(prep_x_kernel, dim3(2048), dim3(256), 0, stream,
                     x, xh, xl);
  hipLaunchKernelGGL(prep_w_kernel, dim3(768), dim3(256), 0, stream,
                     Wq, Wk, Wv, WTh, WTl);
  hipLaunchKernelGGL(proj_kernel, dim3(256, 3), dim3(256), 0, stream,
                     xh, xl, WTh, WTl, bq, bk, bv, Qf, Kf, VT);
  hipLaunchKernelGGL(attn_kernel, dim3(512), dim3(256), 0, stream,
                     Qf, Kf, VT, Opart, Mpart, Lpart);
  hipLaunchKernelGGL(merge_kernel, dim3(2048), dim3(256), 0, stream,
                     Opart, Mpart, Lpart, out);
}